// Round 1
// baseline (5861.248 us; speedup 1.0000x reference)
//
#include <hip/hip_runtime.h>

// Problem constants (from reference)
#define NPTS   8192   // N
#define NPT    2048   // NPOINT
#define NS     32     // NSAMPLE
#define CIN    64
#define BATCH  4
// threshold: f32 nearest to 0.64 (numpy/jax weak-type the python float 0.8**2 to f32)
#define R2     0.64f

// ---------------- prep: transpose weights into ws ----------------
// w1 (128,67) -> w1t (67,128);  w2 (256,128) -> w2t (128,256)
__global__ __launch_bounds__(256) void prep_kernel(const float* __restrict__ w1,
                                                   const float* __restrict__ w2,
                                                   float* __restrict__ w1t,
                                                   float* __restrict__ w2t) {
  int i = blockIdx.x * 256 + threadIdx.x;
  if (i < 128 * 67) {
    int o = i / 67, c = i % 67;
    w1t[c * 128 + o] = w1[i];
  }
  if (i < 256 * 128) {
    int o = i >> 7, c = i & 127;
    w2t[c * 256 + o] = w2[i];
  }
}

// ---------------- FPS: one block per batch, 1024 threads, 8 pts/thread ----------------
// Exact-arithmetic requirement: distances computed as ((dx*dx + dy*dy) + dz*dz) with
// __fmul_rn/__fadd_rn (no FMA contraction) so argmax bit-matches the numpy reference.
// One barrier per iteration; candidate arrays ping-pong (buf = t&1) so a fast wave's
// next-iteration write can never race a slow wave's read.
__global__ __launch_bounds__(1024) void fps_kernel(const float* __restrict__ xyz,
                                                   float* __restrict__ new_xyz) {
  const int b = blockIdx.x;
  const int tid = threadIdx.x;
  const int lane = tid & 63;
  const int wv = tid >> 6;           // 16 waves
  const float* X = xyz + (size_t)b * NPTS * 3;

  __shared__ float cv_s[2][16];
  __shared__ int   ci_s[2][16];
  __shared__ float cx_s[2][16], cy_s[2][16], cz_s[2][16];

  // own 8 points (strided: p = tid + k*1024), coords + running min-dist in registers
  float px[8], py[8], pz[8], dmin[8];
#pragma unroll
  for (int k = 0; k < 8; ++k) {
    int p = tid + (k << 10);
    px[k] = X[p * 3 + 0];
    py[k] = X[p * 3 + 1];
    pz[k] = X[p * 3 + 2];
    dmin[k] = 1e10f;
  }
  // first selected point is index 0
  float cx = X[0], cy = X[1], cz = X[2];
  if (tid == 0) {
    new_xyz[(size_t)b * NPT * 3 + 0] = cx;
    new_xyz[(size_t)b * NPT * 3 + 1] = cy;
    new_xyz[(size_t)b * NPT * 3 + 2] = cz;
  }

  for (int t = 1; t < NPT; ++t) {
    // update min-dists vs current point, track local argmax (ascending index => first-max)
    float bestv = -1.0f;
    int besti = 0;
#pragma unroll
    for (int k = 0; k < 8; ++k) {
      float dx = px[k] - cx, dy = py[k] - cy, dz = pz[k] - cz;
      float d = __fadd_rn(__fadd_rn(__fmul_rn(dx, dx), __fmul_rn(dy, dy)), __fmul_rn(dz, dz));
      float dm = fminf(dmin[k], d);
      dmin[k] = dm;
      bool better = dm > bestv;
      bestv = better ? dm : bestv;
      besti = better ? (tid + (k << 10)) : besti;
    }
    // select local winner's coords (static unroll, no dynamic reg indexing)
    int bk = besti >> 10;
    float bx = px[0], by = py[0], bz = pz[0];
#pragma unroll
    for (int k = 1; k < 8; ++k) {
      bool e = (bk == k);
      bx = e ? px[k] : bx; by = e ? py[k] : by; bz = e ? pz[k] : bz;
    }
    // wave butterfly reduce on (val, idx, x, y, z); ties -> smaller index (numpy argmax)
#pragma unroll
    for (int off = 1; off < 64; off <<= 1) {
      float ov = __shfl_xor(bestv, off);
      int   oi = __shfl_xor(besti, off);
      float ox = __shfl_xor(bx, off);
      float oy = __shfl_xor(by, off);
      float oz = __shfl_xor(bz, off);
      bool take = (ov > bestv) || (ov == bestv && oi < besti);
      bestv = take ? ov : bestv; besti = take ? oi : besti;
      bx = take ? ox : bx; by = take ? oy : by; bz = take ? oz : bz;
    }
    const int buf = t & 1;
    if (lane == 0) {
      cv_s[buf][wv] = bestv; ci_s[buf][wv] = besti;
      cx_s[buf][wv] = bx; cy_s[buf][wv] = by; cz_s[buf][wv] = bz;
    }
    __syncthreads();
    // every wave redundantly reduces the 16 candidates (16-lane groups agree)
    int si = lane & 15;
    float v2 = cv_s[buf][si]; int i2 = ci_s[buf][si];
    float x2 = cx_s[buf][si], y2 = cy_s[buf][si], z2 = cz_s[buf][si];
#pragma unroll
    for (int off = 1; off < 16; off <<= 1) {
      float ov = __shfl_xor(v2, off);
      int   oi = __shfl_xor(i2, off);
      float ox = __shfl_xor(x2, off);
      float oy = __shfl_xor(y2, off);
      float oz = __shfl_xor(z2, off);
      bool take = (ov > v2) || (ov == v2 && oi < i2);
      v2 = take ? ov : v2; i2 = take ? oi : i2;
      x2 = take ? ox : x2; y2 = take ? oy : y2; z2 = take ? oz : z2;
    }
    cx = x2; cy = y2; cz = z2;
    if (tid == 0) {
      new_xyz[((size_t)b * NPT + t) * 3 + 0] = cx;
      new_xyz[((size_t)b * NPT + t) * 3 + 1] = cy;
      new_xyz[((size_t)b * NPT + t) * 3 + 2] = cz;
    }
  }
}

// ---------------- ball query: one wave per (b,s) ----------------
// Scans points in ascending index order (matches top_k over index-score), takes
// first 32 strictly inside R2, pads with the first hit.
__global__ __launch_bounds__(256) void ballquery_kernel(const float* __restrict__ xyz,
                                                        const float* __restrict__ new_xyz,
                                                        int* __restrict__ idx_out) {
  const int w = blockIdx.x * 4 + (threadIdx.x >> 6);   // (b*2048 + s)
  const int lane = threadIdx.x & 63;
  const int b = w >> 11;
  const float* X = xyz + (size_t)b * NPTS * 3;
  const float cx = new_xyz[w * 3 + 0];
  const float cy = new_xyz[w * 3 + 1];
  const float cz = new_xyz[w * 3 + 2];
  int* out = idx_out + (size_t)w * NS;

  int found = 0;
  int first = -1;
  for (int base = 0; base < NPTS; base += 64) {
    const int p = base + lane;
    float x = X[p * 3 + 0], y = X[p * 3 + 1], z = X[p * 3 + 2];
    float dx = x - cx, dy = y - cy, dz = z - cz;
    float d2 = __fadd_rn(__fadd_rn(__fmul_rn(dx, dx), __fmul_rn(dy, dy)), __fmul_rn(dz, dz));
    unsigned long long mask = __ballot(d2 < R2);
    if (mask != 0ull && first < 0) first = base + __ffsll((unsigned long long)mask) - 1;
    if (found < NS) {
      if ((mask >> lane) & 1ull) {
        int rank = found + __popcll(mask & ((1ull << lane) - 1ull));
        if (rank < NS) out[rank] = p;
      }
    }
    found += __popcll(mask);
    if (found >= NS) break;
  }
  if (found < NS) {
    int pad = (first < 0) ? 0 : first;     // ball always non-empty (center itself), but be safe
    if (lane >= found && lane < NS) out[lane] = pad;
  }
}

// ---------------- group + MLP(67->128->256) + maxpool: one block per (b,s) ----------------
__global__ __launch_bounds__(256) void group_mlp_kernel(const float* __restrict__ xyz,
                                                        const float* __restrict__ feat,
                                                        const float* __restrict__ new_xyz,
                                                        const int* __restrict__ idx,
                                                        const float* __restrict__ w1t,
                                                        const float* __restrict__ b1,
                                                        const float* __restrict__ w2t,
                                                        const float* __restrict__ b2,
                                                        float* __restrict__ pooled) {
  const int blk = blockIdx.x;       // b*2048 + s
  const int b = blk >> 11, s = blk & 2047;
  const int tid = threadIdx.x;

  __shared__ __align__(16) float G[67 * 32];    // (C+3) x ns
  __shared__ __align__(16) float H1[128 * 32];  // 128 x ns
  __shared__ int   lidx[NS];
  __shared__ float ctr[3];

  if (tid < NS) lidx[tid] = idx[(size_t)blk * NS + tid];
  if (tid < 3)  ctr[tid] = new_xyz[blk * 3 + tid];
  __syncthreads();

  const float* F = feat + (size_t)b * CIN * NPTS;
  const float* X = xyz + (size_t)b * NPTS * 3;

  // fill G: rows 0..2 = rel xyz, rows 3..66 = gathered features
  for (int e = tid; e < 67 * 32; e += 256) {
    int c = e >> 5, j = e & 31;
    int p = lidx[j];
    float v;
    if (c < 3) v = X[p * 3 + c] - ctr[c];
    else       v = F[(size_t)(c - 3) * NPTS + p];
    G[e] = v;
  }
  __syncthreads();

  // H1 = relu(W1 @ G + b1): 128x32, each thread 4o x 4j
  {
    const int oi = tid >> 3, ji = tid & 7;
    const int o0 = oi * 4, j0 = ji * 4;
    float acc[4][4];
#pragma unroll
    for (int i = 0; i < 4; ++i)
#pragma unroll
      for (int jj = 0; jj < 4; ++jj) acc[i][jj] = 0.f;
#pragma unroll 4
    for (int c = 0; c < 67; ++c) {
      float4 g  = *(const float4*)&G[c * 32 + j0];
      float4 wf = *(const float4*)&w1t[c * 128 + o0];
      float ga[4] = {g.x, g.y, g.z, g.w};
      float wa[4] = {wf.x, wf.y, wf.z, wf.w};
#pragma unroll
      for (int i = 0; i < 4; ++i)
#pragma unroll
        for (int jj = 0; jj < 4; ++jj)
          acc[i][jj] = fmaf(wa[i], ga[jj], acc[i][jj]);
    }
    float4 bb = *(const float4*)&b1[o0];
    float ba[4] = {bb.x, bb.y, bb.z, bb.w};
#pragma unroll
    for (int i = 0; i < 4; ++i) {
      float4 h;
      h.x = fmaxf(acc[i][0] + ba[i], 0.f);
      h.y = fmaxf(acc[i][1] + ba[i], 0.f);
      h.z = fmaxf(acc[i][2] + ba[i], 0.f);
      h.w = fmaxf(acc[i][3] + ba[i], 0.f);
      *(float4*)&H1[(o0 + i) * 32 + j0] = h;
    }
  }
  __syncthreads();

  // H2 = relu(W2 @ H1 + b2): 256x32, each thread 8o x 4j, then maxpool over j
  {
    const int oi = tid >> 3, ji = tid & 7;
    const int o0 = oi * 8, j0 = ji * 4;
    float acc[8][4];
#pragma unroll
    for (int i = 0; i < 8; ++i)
#pragma unroll
      for (int jj = 0; jj < 4; ++jj) acc[i][jj] = 0.f;
#pragma unroll 2
    for (int c = 0; c < 128; ++c) {
      float4 h  = *(const float4*)&H1[c * 32 + j0];
      float4 wa4 = *(const float4*)&w2t[c * 256 + o0];
      float4 wb4 = *(const float4*)&w2t[c * 256 + o0 + 4];
      float ha[4] = {h.x, h.y, h.z, h.w};
      float wa[8] = {wa4.x, wa4.y, wa4.z, wa4.w, wb4.x, wb4.y, wb4.z, wb4.w};
#pragma unroll
      for (int i = 0; i < 8; ++i)
#pragma unroll
        for (int jj = 0; jj < 4; ++jj)
          acc[i][jj] = fmaf(wa[i], ha[jj], acc[i][jj]);
    }
    float4 b2a = *(const float4*)&b2[o0];
    float4 b2b = *(const float4*)&b2[o0 + 4];
    float bb[8] = {b2a.x, b2a.y, b2a.z, b2a.w, b2b.x, b2b.y, b2b.z, b2b.w};
    float m[8];
#pragma unroll
    for (int i = 0; i < 8; ++i) {
      float v0 = fmaxf(acc[i][0] + bb[i], 0.f);
      float v1 = fmaxf(acc[i][1] + bb[i], 0.f);
      float v2 = fmaxf(acc[i][2] + bb[i], 0.f);
      float v3 = fmaxf(acc[i][3] + bb[i], 0.f);
      m[i] = fmaxf(fmaxf(v0, v1), fmaxf(v2, v3));
    }
    // reduce across the 8 ji-threads (adjacent lanes within a wave)
#pragma unroll
    for (int off = 1; off < 8; off <<= 1)
#pragma unroll
      for (int i = 0; i < 8; ++i) m[i] = fmaxf(m[i], __shfl_xor(m[i], off));
    if (ji == 0) {
#pragma unroll
      for (int i = 0; i < 8; ++i)
        pooled[((size_t)b * 256 + o0 + i) * (size_t)NPT + s] = m[i];
    }
  }
}

extern "C" void kernel_launch(void* const* d_in, const int* in_sizes, int n_in,
                              void* d_out, int out_size, void* d_ws, size_t ws_size,
                              hipStream_t stream) {
  (void)in_sizes; (void)n_in; (void)out_size; (void)ws_size;
  const float* xyz  = (const float*)d_in[0];   // (4,8192,3)
  const float* feat = (const float*)d_in[1];   // (4,64,8192)
  const float* w1   = (const float*)d_in[2];   // (128,67)
  const float* b1   = (const float*)d_in[3];   // (128)
  const float* w2   = (const float*)d_in[4];   // (256,128)
  const float* b2   = (const float*)d_in[5];   // (256)

  float* out     = (float*)d_out;
  float* new_xyz = out;                        // (4,2048,3) = 24576 floats
  float* pooled  = out + (size_t)BATCH * NPT * 3;  // (4,256,2048)

  char* ws = (char*)d_ws;
  float* w1t = (float*)ws;                             // 67*128 floats  = 34304 B
  float* w2t = (float*)(ws + 34304);                   // 128*256 floats = 131072 B
  int*   idx = (int*)(ws + 34304 + 131072);            // 4*2048*32 ints = 1 MB

  prep_kernel<<<128, 256, 0, stream>>>(w1, w2, w1t, w2t);
  fps_kernel<<<BATCH, 1024, 0, stream>>>(xyz, new_xyz);
  ballquery_kernel<<<(BATCH * NPT) / 4, 256, 0, stream>>>(xyz, new_xyz, idx);
  group_mlp_kernel<<<BATCH * NPT, 256, 0, stream>>>(xyz, feat, new_xyz, idx,
                                                    w1t, b1, w2t, b2, pooled);
}

// Round 2
// 2855.619 us; speedup vs baseline: 2.0525x; 2.0525x over previous
//
#include <hip/hip_runtime.h>

// Problem constants (from reference)
#define NPTS   8192   // N
#define NPT    2048   // NPOINT
#define NS     32     // NSAMPLE
#define CIN    64
#define BATCH  4
// threshold: f32 nearest to 0.64 (numpy/jax weak-type the python float 0.8**2 to f32)
#define R2     0.64f

// ---------------- prep: transpose weights into ws ----------------
__global__ __launch_bounds__(256) void prep_kernel(const float* __restrict__ w1,
                                                   const float* __restrict__ w2,
                                                   float* __restrict__ w1t,
                                                   float* __restrict__ w2t) {
  int i = blockIdx.x * 256 + threadIdx.x;
  if (i < 128 * 67) {
    int o = i / 67, c = i % 67;
    w1t[c * 128 + o] = w1[i];
  }
  if (i < 256 * 128) {
    int o = i >> 7, c = i & 127;
    w2t[c * 256 + o] = w2[i];
  }
}

// ---------------- FPS v2: DPP row_ror argmax on packed u64 keys ----------------
// key = (float_bits(dist) << 13) | (8191 - idx): dist >= 0 so uint order == float
// order; max(key) = max dist with ties -> smallest idx (numpy argmax semantics).
// Intra-row (16 lanes) reduction via 4 DPP row_ror steps (pure VALU, no LDS pipe).
// 64 row-winners -> LDS; one barrier; every wave redundantly reduces the 64 keys
// (row_ror again + readlane), so no second barrier / broadcast is needed. Winner
// coords come from a wave-uniform (scalar) load of X[sidx].
// rec ping-pongs on t&1 so a fast wave's next-iteration write can't clobber a
// slow wave's read.

#define DPP_ROR_STEP(kvar, ctrl)                                               \
  {                                                                            \
    int _lo = (int)(uint32_t)(kvar);                                           \
    int _hi = (int)(uint32_t)((kvar) >> 32);                                   \
    int _olo = __builtin_amdgcn_update_dpp(0, _lo, (ctrl), 0xF, 0xF, false);   \
    int _ohi = __builtin_amdgcn_update_dpp(0, _hi, (ctrl), 0xF, 0xF, false);   \
    uint64_t _o = ((uint64_t)(uint32_t)_ohi << 32) | (uint32_t)_olo;           \
    if (_o > (kvar)) (kvar) = _o;                                              \
  }

#define ROW_MAX_U64(kvar)                                                      \
  DPP_ROR_STEP(kvar, 0x121)  /* row_ror:1 */                                   \
  DPP_ROR_STEP(kvar, 0x122)  /* row_ror:2 */                                   \
  DPP_ROR_STEP(kvar, 0x124)  /* row_ror:4 */                                   \
  DPP_ROR_STEP(kvar, 0x128)  /* row_ror:8 */

__global__ __launch_bounds__(1024) void fps_kernel(const float* __restrict__ xyz,
                                                   float* __restrict__ new_xyz) {
  const int b = blockIdx.x;
  const int tid = threadIdx.x;
  const int lane = tid & 63;
  const int wv = tid >> 6;                 // 16 waves
  const int rowid = wv * 4 + (lane >> 4);  // 0..63 global row id
  const float* X = xyz + (size_t)b * NPTS * 3;

  __shared__ uint64_t rec[2][64];

  // own 8 points (p = tid + k*1024): coords + running min-dist in registers
  float px[8], py[8], pz[8], dmin[8];
#pragma unroll
  for (int k = 0; k < 8; ++k) {
    int p = tid + (k << 10);
    px[k] = X[p * 3 + 0];
    py[k] = X[p * 3 + 1];
    pz[k] = X[p * 3 + 2];
    dmin[k] = 1e10f;
  }
  float cx = X[0], cy = X[1], cz = X[2];
  if (tid == 0) {
    new_xyz[(size_t)b * NPT * 3 + 0] = cx;
    new_xyz[(size_t)b * NPT * 3 + 1] = cy;
    new_xyz[(size_t)b * NPT * 3 + 2] = cz;
  }

  for (int t = 1; t < NPT; ++t) {
    // exact-rounding distance update + local argmax (strict > keeps smallest idx)
    float bestv = -1.0f;
    int besti = 0;
#pragma unroll
    for (int k = 0; k < 8; ++k) {
      float dx = px[k] - cx, dy = py[k] - cy, dz = pz[k] - cz;
      float d = __fadd_rn(__fadd_rn(__fmul_rn(dx, dx), __fmul_rn(dy, dy)), __fmul_rn(dz, dz));
      float dm = fminf(dmin[k], d);
      dmin[k] = dm;
      if (dm > bestv) { bestv = dm; besti = tid + (k << 10); }
    }
    uint64_t key = ((uint64_t)__float_as_uint(bestv) << 13) | (uint32_t)(8191 - besti);

    // intra-row (16-lane) max: 4 DPP steps, all lanes end with their row's winner
    ROW_MAX_U64(key)

    const int buf = t & 1;
    if ((lane & 15) == 0) rec[buf][rowid] = key;
    __syncthreads();

    // every wave redundantly reduces the 64 row-winners (no 2nd barrier needed)
    uint64_t k2 = rec[buf][lane];
    ROW_MAX_U64(k2)
    uint32_t lo2 = (uint32_t)k2, hi2 = (uint32_t)(k2 >> 32);
    uint64_t w0 = ((uint64_t)(uint32_t)__builtin_amdgcn_readlane((int)hi2, 0)  << 32) | (uint32_t)__builtin_amdgcn_readlane((int)lo2, 0);
    uint64_t w1 = ((uint64_t)(uint32_t)__builtin_amdgcn_readlane((int)hi2, 16) << 32) | (uint32_t)__builtin_amdgcn_readlane((int)lo2, 16);
    uint64_t w2 = ((uint64_t)(uint32_t)__builtin_amdgcn_readlane((int)hi2, 32) << 32) | (uint32_t)__builtin_amdgcn_readlane((int)lo2, 32);
    uint64_t w3 = ((uint64_t)(uint32_t)__builtin_amdgcn_readlane((int)hi2, 48) << 32) | (uint32_t)__builtin_amdgcn_readlane((int)lo2, 48);
    uint64_t wk = w0;
    if (w1 > wk) wk = w1;
    if (w2 > wk) wk = w2;
    if (w3 > wk) wk = w3;

    int sidx = 8191 - (int)(wk & 8191u);   // wave-uniform winner index
    const float* P = X + 3 * (size_t)sidx; // uniform -> scalar loads
    cx = P[0]; cy = P[1]; cz = P[2];

    if (tid == 0) {
      float* o = new_xyz + ((size_t)b * NPT + t) * 3;
      o[0] = cx; o[1] = cy; o[2] = cz;
    }
  }
}

// ---------------- ball query: one wave per (b,s) ----------------
__global__ __launch_bounds__(256) void ballquery_kernel(const float* __restrict__ xyz,
                                                        const float* __restrict__ new_xyz,
                                                        int* __restrict__ idx_out) {
  const int w = blockIdx.x * 4 + (threadIdx.x >> 6);   // (b*2048 + s)
  const int lane = threadIdx.x & 63;
  const int b = w >> 11;
  const float* X = xyz + (size_t)b * NPTS * 3;
  const float cx = new_xyz[w * 3 + 0];
  const float cy = new_xyz[w * 3 + 1];
  const float cz = new_xyz[w * 3 + 2];
  int* out = idx_out + (size_t)w * NS;

  int found = 0;
  int first = -1;
  for (int base = 0; base < NPTS; base += 64) {
    const int p = base + lane;
    float x = X[p * 3 + 0], y = X[p * 3 + 1], z = X[p * 3 + 2];
    float dx = x - cx, dy = y - cy, dz = z - cz;
    float d2 = __fadd_rn(__fadd_rn(__fmul_rn(dx, dx), __fmul_rn(dy, dy)), __fmul_rn(dz, dz));
    unsigned long long mask = __ballot(d2 < R2);
    if (mask != 0ull && first < 0) first = base + __ffsll((unsigned long long)mask) - 1;
    if (found < NS) {
      if ((mask >> lane) & 1ull) {
        int rank = found + __popcll(mask & ((1ull << lane) - 1ull));
        if (rank < NS) out[rank] = p;
      }
    }
    found += __popcll(mask);
    if (found >= NS) break;
  }
  if (found < NS) {
    int pad = (first < 0) ? 0 : first;
    if (lane >= found && lane < NS) out[lane] = pad;
  }
}

// ---------------- group + MLP(67->128->256) + maxpool: one block per (b,s) ----------------
__global__ __launch_bounds__(256) void group_mlp_kernel(const float* __restrict__ xyz,
                                                        const float* __restrict__ feat,
                                                        const float* __restrict__ new_xyz,
                                                        const int* __restrict__ idx,
                                                        const float* __restrict__ w1t,
                                                        const float* __restrict__ b1,
                                                        const float* __restrict__ w2t,
                                                        const float* __restrict__ b2,
                                                        float* __restrict__ pooled) {
  const int blk = blockIdx.x;       // b*2048 + s
  const int b = blk >> 11, s = blk & 2047;
  const int tid = threadIdx.x;

  __shared__ __align__(16) float G[67 * 32];    // (C+3) x ns
  __shared__ __align__(16) float H1[128 * 32];  // 128 x ns
  __shared__ int   lidx[NS];
  __shared__ float ctr[3];

  if (tid < NS) lidx[tid] = idx[(size_t)blk * NS + tid];
  if (tid < 3)  ctr[tid] = new_xyz[blk * 3 + tid];
  __syncthreads();

  const float* F = feat + (size_t)b * CIN * NPTS;
  const float* X = xyz + (size_t)b * NPTS * 3;

  for (int e = tid; e < 67 * 32; e += 256) {
    int c = e >> 5, j = e & 31;
    int p = lidx[j];
    float v;
    if (c < 3) v = X[p * 3 + c] - ctr[c];
    else       v = F[(size_t)(c - 3) * NPTS + p];
    G[e] = v;
  }
  __syncthreads();

  // H1 = relu(W1 @ G + b1): 128x32, each thread 4o x 4j
  {
    const int oi = tid >> 3, ji = tid & 7;
    const int o0 = oi * 4, j0 = ji * 4;
    float acc[4][4];
#pragma unroll
    for (int i = 0; i < 4; ++i)
#pragma unroll
      for (int jj = 0; jj < 4; ++jj) acc[i][jj] = 0.f;
#pragma unroll 4
    for (int c = 0; c < 67; ++c) {
      float4 g  = *(const float4*)&G[c * 32 + j0];
      float4 wf = *(const float4*)&w1t[c * 128 + o0];
      float ga[4] = {g.x, g.y, g.z, g.w};
      float wa[4] = {wf.x, wf.y, wf.z, wf.w};
#pragma unroll
      for (int i = 0; i < 4; ++i)
#pragma unroll
        for (int jj = 0; jj < 4; ++jj)
          acc[i][jj] = fmaf(wa[i], ga[jj], acc[i][jj]);
    }
    float4 bb = *(const float4*)&b1[o0];
    float ba[4] = {bb.x, bb.y, bb.z, bb.w};
#pragma unroll
    for (int i = 0; i < 4; ++i) {
      float4 h;
      h.x = fmaxf(acc[i][0] + ba[i], 0.f);
      h.y = fmaxf(acc[i][1] + ba[i], 0.f);
      h.z = fmaxf(acc[i][2] + ba[i], 0.f);
      h.w = fmaxf(acc[i][3] + ba[i], 0.f);
      *(float4*)&H1[(o0 + i) * 32 + j0] = h;
    }
  }
  __syncthreads();

  // H2 = relu(W2 @ H1 + b2): 256x32, each thread 8o x 4j, then maxpool over j
  {
    const int oi = tid >> 3, ji = tid & 7;
    const int o0 = oi * 8, j0 = ji * 4;
    float acc[8][4];
#pragma unroll
    for (int i = 0; i < 8; ++i)
#pragma unroll
      for (int jj = 0; jj < 4; ++jj) acc[i][jj] = 0.f;
#pragma unroll 2
    for (int c = 0; c < 128; ++c) {
      float4 h  = *(const float4*)&H1[c * 32 + j0];
      float4 wa4 = *(const float4*)&w2t[c * 256 + o0];
      float4 wb4 = *(const float4*)&w2t[c * 256 + o0 + 4];
      float ha[4] = {h.x, h.y, h.z, h.w};
      float wa[8] = {wa4.x, wa4.y, wa4.z, wa4.w, wb4.x, wb4.y, wb4.z, wb4.w};
#pragma unroll
      for (int i = 0; i < 8; ++i)
#pragma unroll
        for (int jj = 0; jj < 4; ++jj)
          acc[i][jj] = fmaf(wa[i], ha[jj], acc[i][jj]);
    }
    float4 b2a = *(const float4*)&b2[o0];
    float4 b2b = *(const float4*)&b2[o0 + 4];
    float bb[8] = {b2a.x, b2a.y, b2a.z, b2a.w, b2b.x, b2b.y, b2b.z, b2b.w};
    float m[8];
#pragma unroll
    for (int i = 0; i < 8; ++i) {
      float v0 = fmaxf(acc[i][0] + bb[i], 0.f);
      float v1 = fmaxf(acc[i][1] + bb[i], 0.f);
      float v2 = fmaxf(acc[i][2] + bb[i], 0.f);
      float v3 = fmaxf(acc[i][3] + bb[i], 0.f);
      m[i] = fmaxf(fmaxf(v0, v1), fmaxf(v2, v3));
    }
#pragma unroll
    for (int off = 1; off < 8; off <<= 1)
#pragma unroll
      for (int i = 0; i < 8; ++i) m[i] = fmaxf(m[i], __shfl_xor(m[i], off));
    if (ji == 0) {
#pragma unroll
      for (int i = 0; i < 8; ++i)
        pooled[((size_t)b * 256 + o0 + i) * (size_t)NPT + s] = m[i];
    }
  }
}

extern "C" void kernel_launch(void* const* d_in, const int* in_sizes, int n_in,
                              void* d_out, int out_size, void* d_ws, size_t ws_size,
                              hipStream_t stream) {
  (void)in_sizes; (void)n_in; (void)out_size; (void)ws_size;
  const float* xyz  = (const float*)d_in[0];   // (4,8192,3)
  const float* feat = (const float*)d_in[1];   // (4,64,8192)
  const float* w1   = (const float*)d_in[2];   // (128,67)
  const float* b1   = (const float*)d_in[3];   // (128)
  const float* w2   = (const float*)d_in[4];   // (256,128)
  const float* b2   = (const float*)d_in[5];   // (256)

  float* out     = (float*)d_out;
  float* new_xyz = out;                        // (4,2048,3)
  float* pooled  = out + (size_t)BATCH * NPT * 3;  // (4,256,2048)

  char* ws = (char*)d_ws;
  float* w1t = (float*)ws;                             // 67*128 floats
  float* w2t = (float*)(ws + 34304);                   // 128*256 floats
  int*   idx = (int*)(ws + 34304 + 131072);            // 4*2048*32 ints

  prep_kernel<<<128, 256, 0, stream>>>(w1, w2, w1t, w2t);
  fps_kernel<<<BATCH, 1024, 0, stream>>>(xyz, new_xyz);
  ballquery_kernel<<<(BATCH * NPT) / 4, 256, 0, stream>>>(xyz, new_xyz, idx);
  group_mlp_kernel<<<BATCH * NPT, 256, 0, stream>>>(xyz, feat, new_xyz, idx,
                                                    w1t, b1, w2t, b2, pooled);
}